// Round 6
// baseline (972.370 us; speedup 1.0000x reference)
//
#include <hip/hip_runtime.h>
#include <hip/hip_bf16.h>
#include <math.h>

typedef __hip_bfloat16 bf16;

#define SCALE_QK 0.17677669529663687f  /* 32^-0.5 */

__device__ __forceinline__ float b2f(bf16 v){ return __bfloat162float(v); }
__device__ __forceinline__ bf16  f2b(float v){ return __float2bfloat16(v); }
__device__ __forceinline__ short bfs(float x){ bf16 b = f2b(x); short s; __builtin_memcpy(&s, &b, 2); return s; }

struct __align__(16) bf16x8 { bf16 v[8]; };

typedef __attribute__((ext_vector_type(8))) short sh8;
typedef __attribute__((ext_vector_type(4))) short sh4;
typedef __attribute__((ext_vector_type(4))) float f4;

#if defined(__has_builtin)
#if __has_builtin(__builtin_amdgcn_mfma_f32_16x16x16bf16_1k)
#define HAS_MFMA16 1
#else
#define HAS_MFMA16 0
#endif
#else
#define HAS_MFMA16 0
#endif

// ---------------------------------------------------------------- all 8 weight tensors f32 -> bf16, one launch
__global__ __launch_bounds__(256) void wcvt8_k(const float* s0, const float* s1, const float* s2, const float* s3,
                                               const float* s4, const float* s5, const float* s6, const float* s7,
                                               bf16* d0, bf16* d1, bf16* d2, bf16* d3,
                                               bf16* d4, bf16* d5, bf16* d6, bf16* d7) {
    const int sizes[8] = {196608, 65536, 262144, 262144, 196608, 65536, 262144, 262144};
    int which = blockIdx.y;
    const float* s; bf16* d;
    switch (which) {
        case 0: s = s0; d = d0; break;  case 1: s = s1; d = d1; break;
        case 2: s = s2; d = d2; break;  case 3: s = s3; d = d3; break;
        case 4: s = s4; d = d4; break;  case 5: s = s5; d = d5; break;
        case 6: s = s6; d = d6; break;  default: s = s7; d = d7; break;
    }
    int i = blockIdx.x * 256 + threadIdx.x;
    if (i < sizes[which]) d[i] = f2b(s[i]);
}

// ---------------------------------------------------------------- pos-emb MLP (both tables, y picks)
__global__ __launch_bounds__(256) void posmlp_k(const float* __restrict__ w1a, const float* __restrict__ b1a,
                                                const float* __restrict__ w2a, float* __restrict__ outa,
                                                const float* __restrict__ w1b, const float* __restrict__ b1b,
                                                const float* __restrict__ w2b, float* __restrict__ outb) {
    const float* w1 = blockIdx.y ? w1b : w1a;
    const float* b1 = blockIdx.y ? b1b : b1a;
    const float* w2 = blockIdx.y ? w2b : w2a;
    float* out      = blockIdx.y ? outb : outa;
    int t = blockIdx.x, tid = threadIdx.x;
    __shared__ float hid[512];
    int i = t >> 6, j = (t >> 3) & 7, k = t & 7;
    float c0 = (i - 4) * 0.25f, c1 = (j - 4) * 0.25f, c2 = (k - 4) * 0.25f;
    for (int jj = tid; jj < 512; jj += 256) {
        float h = c0 * w1[jj*3+0] + c1 * w1[jj*3+1] + c2 * w1[jj*3+2] + b1[jj];
        hid[jj] = fmaxf(h, 0.f);
    }
    __syncthreads();
    float acc = 0.f;
    const float* w2r = w2 + (size_t)tid * 512;
    for (int jj = 0; jj < 512; jj++) acc += hid[jj] * w2r[jj];
    out[(size_t)t * 256 + tid] = acc;
}

// ---------------------------------------------------------------- CPB table MLP (both tables, y picks)
__device__ __forceinline__ float cpb_coord(int idx) {
    float v = (idx - 7) * (8.0f / 7.0f);
    return copysignf(log2f(fabsf(v) + 1.0f) * (1.0f / 3.0f), v);
}
__global__ __launch_bounds__(512) void cpbtab_k(const float* __restrict__ w1a, const float* __restrict__ b1a,
                                                const float* __restrict__ w2a, float* __restrict__ taba,
                                                const float* __restrict__ w1b, const float* __restrict__ b1b,
                                                const float* __restrict__ w2b, float* __restrict__ tabb) {
    const float* w1 = blockIdx.y ? w1b : w1a;
    const float* b1 = blockIdx.y ? b1b : b1a;
    const float* w2 = blockIdx.y ? w2b : w2a;
    float* tab      = blockIdx.y ? tabb : taba;
    int t = blockIdx.x, tid = threadIdx.x;
    __shared__ float hid[512];
    int i = t / 225, r = t - i * 225, j = r / 15, k = r - j * 15;
    float x0 = cpb_coord(i), x1 = cpb_coord(j), x2 = cpb_coord(k);
    float h = x0 * w1[tid*3+0] + x1 * w1[tid*3+1] + x2 * w1[tid*3+2] + b1[tid];
    hid[tid] = fmaxf(h, 0.f);
    __syncthreads();
    int h8 = tid >> 6, lane = tid & 63;
    float p = 0.f;
    for (int jj = lane; jj < 512; jj += 64) p += hid[jj] * w2[h8*512 + jj];
    for (int off = 32; off; off >>= 1) p += __shfl_down(p, off);
    if (lane == 0) tab[t * 8 + h8] = p;
}

// ---------------------------------------------------------------- bias materialize (both tables), biasT[h][k][q]
__global__ __launch_bounds__(256) void biasbuild_k(const float* __restrict__ taba, float* __restrict__ biasTa,
                                                   const float* __restrict__ tabb, float* __restrict__ biasTb) {
    const float* tab = blockIdx.y ? tabb : taba;
    float* biasT     = blockIdx.y ? biasTb : biasTa;
    int idx = blockIdx.x * 256 + threadIdx.x;      // 8*512*512 total
    int h = idx >> 18, rem = idx & 262143;
    int kq = rem >> 9, p = rem & 511;              // kq = key token, p = query token
    int px = p >> 6, py = (p >> 3) & 7, pz = p & 7;
    int qx = kq >> 6, qy = (kq >> 3) & 7, qz = kq & 7;
    int tidx = ((px - qx + 7) * 15 + (py - qy + 7)) * 15 + (pz - qz + 7);
    float v = tab[tidx * 8 + h];
    biasT[idx] = 16.f / (1.f + __expf(-v));
}

// ---------------------------------------------------------------- ct dewindow + hpe (f32)
__global__ __launch_bounds__(256) void ct0build_k(const float* __restrict__ ct_in,
                                                  const float* __restrict__ hpe,
                                                  float* __restrict__ ct0) {
    int u = blockIdx.x, c = threadIdx.x;
    int a = u >> 7, cc = (u >> 5) & 3, e = (u >> 4) & 1, b = (u >> 2) & 3, d = (u >> 1) & 1, f = u & 1;
    int t = a * 128 + b * 32 + cc * 8 + d * 4 + e * 2 + f;
    ct0[(size_t)u * 256 + c] = ct_in[(size_t)t * 256 + c] + hpe[(size_t)u * 256 + c];
}

// ---------------------------------------------------------------- LayerNorm f32 -> bf16
__global__ __launch_bounds__(256) void ln_k(const float* __restrict__ in,
                                            const float* __restrict__ g,
                                            const float* __restrict__ b,
                                            bf16* __restrict__ out) {
    int row = blockIdx.x, c = threadIdx.x;
    float x = in[(size_t)row * 256 + c];
    float s = x, s2 = x * x;
    for (int off = 32; off; off >>= 1) { s += __shfl_down(s, off); s2 += __shfl_down(s2, off); }
    __shared__ float red[8];
    int wid = c >> 6, lane = c & 63;
    if (lane == 0) { red[wid] = s; red[wid + 4] = s2; }
    __syncthreads();
    if (c == 0) { red[0] = red[0] + red[1] + red[2] + red[3]; red[4] = red[4] + red[5] + red[6] + red[7]; }
    __syncthreads();
    float mean = red[0] * (1.f / 256.f);
    float var  = fmaxf(red[4] * (1.f / 256.f) - mean * mean, 0.f);
    float rstd = rsqrtf(var + 1e-5f);
    out[(size_t)row * 256 + c] = f2b((x - mean) * rstd * g[c] + b[c]);
}

// ---------------------------------------------------------------- MFMA GEMM, no LDS, no barriers.
// C = A(MxK,bf16) @ W(NxK,bf16)^T + bias. 128x128 tile, 4 waves = 2x2 quadrants of 64x64.
// Fragments read straight from global (contiguous 16B/lane, L1/L2-resident weights);
// zero __syncthreads in K-loop -> compiler pipelines VMEM under MFMA.
// MODE 0: bf16 store   MODE 1: bf16 GELU store   MODE 2: += f32 residual
template <int MODE>
__global__ __launch_bounds__(256) void gemm_k(const bf16* __restrict__ A,
                                              const bf16* __restrict__ W,
                                              const float* __restrict__ bias,
                                              int M, int N, int K,
                                              float* __restrict__ res,
                                              bf16* __restrict__ outb) {
    int m0 = blockIdx.y * 128, n0 = blockIdx.x * 128;
    int tid = threadIdx.x;
    int lane = tid & 63, wave = tid >> 6;
    int quad = lane >> 4, m16 = lane & 15;
    int wm = (wave & 1) * 64, wn = (wave >> 1) * 64;

    const bf16* Ab = A + (size_t)(m0 + wm + m16) * K + quad * 8;
    const bf16* Wb = W + (size_t)(n0 + wn + m16) * K + quad * 8;

    f4 acc[4][4];
    #pragma unroll
    for (int i = 0; i < 4; i++)
        #pragma unroll
        for (int j = 0; j < 4; j++) acc[i][j] = (f4){0.f, 0.f, 0.f, 0.f};

    for (int k0 = 0; k0 < K; k0 += 32) {
        sh8 af[4], bf[4];
        #pragma unroll
        for (int mi = 0; mi < 4; mi++)
            af[mi] = *reinterpret_cast<const sh8*>(Ab + (size_t)(mi * 16) * K + k0);
        #pragma unroll
        for (int ni = 0; ni < 4; ni++)
            bf[ni] = *reinterpret_cast<const sh8*>(Wb + (size_t)(ni * 16) * K + k0);
        #pragma unroll
        for (int mi = 0; mi < 4; mi++)
            #pragma unroll
            for (int ni = 0; ni < 4; ni++)
                acc[mi][ni] = __builtin_amdgcn_mfma_f32_16x16x32_bf16(af[mi], bf[ni], acc[mi][ni], 0, 0, 0);
    }
    (void)M;

    #pragma unroll
    for (int mi = 0; mi < 4; mi++) {
        #pragma unroll
        for (int r = 0; r < 4; r++) {
            int gm = m0 + wm + mi * 16 + quad * 4 + r;
            #pragma unroll
            for (int ni = 0; ni < 4; ni++) {
                int gn = n0 + wn + ni * 16 + m16;
                float v = acc[mi][ni][r] + bias[gn];
                if (MODE == 2)      res[(size_t)gm * N + gn] += v;
                else if (MODE == 1) outb[(size_t)gm * N + gn] = f2b(0.5f * v * (1.0f + erff(v * 0.70710678118654752f)));
                else                outb[(size_t)gm * N + gn] = f2b(v);
            }
        }
    }
}

// ---------------------------------------------------------------- MFMA flash attention, 32-token k-tiles
// qkv: [win][N][768] bf16 (q|k|v blocks of 256, head h at h*32)
// biasT: [8][512][512] f32 = bias[h][key][query]; out: [win][N][256] bf16
// grid (wh, qs): 8 waves/block; wave handles q-tiles qt = wave + 8*qs, stride 8*QS.
// Per iteration: 2 score MFMAs (32 tokens) + ONE softmax update + 4 PV MFMAs.
#define VSTR 548   /* shorts; 274 dwords, gcd(274%32,32)=2 -> max 2-way (free), 8B-aligned */
__global__ __launch_bounds__(512) void flash_k(const bf16* __restrict__ qkv,
                                               const float* __restrict__ biasT,
                                               bf16* __restrict__ out,
                                               int N, int glob) {
    int wh = blockIdx.x, w = wh >> 3, h = wh & 7;
    int qs = blockIdx.y, QS = gridDim.y;
    int tid = threadIdx.x;
    int lane = tid & 63, wave = tid >> 6;
    int quad = lane >> 4, qcol = lane & 15;
    const int NT32 = (N + 31) & ~31;        // 544 (main) or 512 (hat)

    __shared__ bf16  Vt[32 * VSTR];         // V^T [d][tok]
    __shared__ float Osm[8 * 528];          // per-wave O transpose scratch [16q][33]
#if !HAS_MFMA16
    __shared__ float Ps[8][16 * 17];
#endif

    // stage V^T (zero-pad toks N..NT32)
    for (int i = tid; i < NT32 * 4; i += 512) {
        int tok = i >> 2, seg = i & 3;
        if (tok < N) {
            const bf16* vp = qkv + ((size_t)(w * N + tok)) * 768 + 512 + h * 32 + seg * 8;
            bf16x8 vv = *reinterpret_cast<const bf16x8*>(vp);
            #pragma unroll
            for (int e = 0; e < 8; e++) Vt[(seg * 8 + e) * VSTR + tok] = vv.v[e];
        } else {
            bf16 z = f2b(0.f);
            #pragma unroll
            for (int e = 0; e < 8; e++) Vt[(seg * 8 + e) * VSTR + tok] = z;
        }
    }
    __syncthreads();

    const bf16* qbase = qkv + ((size_t)w * N) * 768 + h * 32;
    const bf16* kbase = qbase + 256;
    int nqt = (N + 15) >> 4, nkt = NT32 >> 5;

    for (int qt = wave + 8 * qs; qt < nqt; qt += 8 * QS) {
        int q_idx = qt * 16 + qcol;
        int q_rd  = (q_idx < N) ? q_idx : (N - 1);     // clamp; garbage cols masked at store
        sh8 qfrag = *reinterpret_cast<const sh8*>(qbase + (size_t)q_rd * 768 + quad * 8);
        f4 O0 = {0.f, 0.f, 0.f, 0.f}, O1 = {0.f, 0.f, 0.f, 0.f};
        float mval = -3.0e38f, l = 0.f;

        for (int kt = 0; kt < nkt; kt++) {
            int bt = kt * 32;
            int k0 = bt + qcol, k1 = bt + 16 + qcol;
            sh8 kf0 = *reinterpret_cast<const sh8*>(kbase + (size_t)((k0 < N) ? k0 : (N - 1)) * 768 + quad * 8);
            sh8 kf1 = *reinterpret_cast<const sh8*>(kbase + (size_t)((k1 < N) ? k1 : (N - 1)) * 768 + quad * 8);
            f4 z = {0.f, 0.f, 0.f, 0.f};
            f4 s0 = __builtin_amdgcn_mfma_f32_16x16x32_bf16(kf0, qfrag, z, 0, 0, 0);
            f4 s1 = __builtin_amdgcn_mfma_f32_16x16x32_bf16(kf1, qfrag, z, 0, 0, 0);

            float vals[8];
            #pragma unroll
            for (int r = 0; r < 4; r++) {
                int tok = bt + quad * 4 + r;
                float bb = 0.f;
                if (tok < N && q_idx < N && tok >= glob && q_idx >= glob)
                    bb = biasT[((size_t)h << 18) + ((size_t)(tok - glob) << 9) + (q_idx - glob)];
                vals[r] = (tok < N) ? (s0[r] * SCALE_QK + bb) : -1e30f;
            }
            #pragma unroll
            for (int r = 0; r < 4; r++) {
                int tok = bt + 16 + quad * 4 + r;
                float bb = 0.f;
                if (tok < N && q_idx < N && tok >= glob && q_idx >= glob)
                    bb = biasT[((size_t)h << 18) + ((size_t)(tok - glob) << 9) + (q_idx - glob)];
                vals[4 + r] = (tok < N) ? (s1[r] * SCALE_QK + bb) : -1e30f;
            }
            float tmax = vals[0];
            #pragma unroll
            for (int r = 1; r < 8; r++) tmax = fmaxf(tmax, vals[r]);
            tmax = fmaxf(tmax, __shfl_xor(tmax, 16));
            tmax = fmaxf(tmax, __shfl_xor(tmax, 32));
            float mnew = fmaxf(mval, tmax);
            float alpha = __expf(mval - mnew);
            float p[8];
            #pragma unroll
            for (int r = 0; r < 8; r++) p[r] = __expf(vals[r] - mnew);
            float ps = 0.f;
            #pragma unroll
            for (int r = 0; r < 8; r++) ps += p[r];
            ps += __shfl_xor(ps, 16);
            ps += __shfl_xor(ps, 32);
            l = l * alpha + ps;
            mval = mnew;
            #pragma unroll
            for (int r = 0; r < 4; r++) { O0[r] *= alpha; O1[r] *= alpha; }

#if HAS_MFMA16
            sh4 pf0, pf1;
            #pragma unroll
            for (int r = 0; r < 4; r++) { pf0[r] = bfs(p[r]); pf1[r] = bfs(p[4 + r]); }
            sh4 v00 = *reinterpret_cast<const sh4*>(&Vt[qcol * VSTR + bt + quad * 4]);
            sh4 v10 = *reinterpret_cast<const sh4*>(&Vt[qcol * VSTR + bt + 16 + quad * 4]);
            sh4 v01 = *reinterpret_cast<const sh4*>(&Vt[(qcol + 16) * VSTR + bt + quad * 4]);
            sh4 v11 = *reinterpret_cast<const sh4*>(&Vt[(qcol + 16) * VSTR + bt + 16 + quad * 4]);
            O0 = __builtin_amdgcn_mfma_f32_16x16x16bf16_1k(v00, pf0, O0, 0, 0, 0);
            O0 = __builtin_amdgcn_mfma_f32_16x16x16bf16_1k(v10, pf1, O0, 0, 0, 0);
            O1 = __builtin_amdgcn_mfma_f32_16x16x16bf16_1k(v01, pf0, O1, 0, 0, 0);
            O1 = __builtin_amdgcn_mfma_f32_16x16x16bf16_1k(v11, pf1, O1, 0, 0, 0);
#else
            for (int half = 0; half < 2; half++) {
                #pragma unroll
                for (int r = 0; r < 4; r++) Ps[wave][(quad * 4 + r) * 17 + qcol] = p[half * 4 + r];
                __builtin_amdgcn_wave_barrier();
                sh8 pbig, va, vb;
                #pragma unroll
                for (int j = 0; j < 8; j++) {
                    int tl = quad * 8 + j;
                    float pv = (quad < 2) ? Ps[wave][tl * 17 + qcol] : 0.f;
                    pbig[j] = bfs(pv);
                    bf16 a0 = (quad < 2) ? Vt[qcol * VSTR + bt + half * 16 + tl] : f2b(0.f);
                    bf16 a1 = (quad < 2) ? Vt[(qcol + 16) * VSTR + bt + half * 16 + tl] : f2b(0.f);
                    short t0, t1;
                    __builtin_memcpy(&t0, &a0, 2); __builtin_memcpy(&t1, &a1, 2);
                    va[j] = t0; vb[j] = t1;
                }
                O0 = __builtin_amdgcn_mfma_f32_16x16x32_bf16(va, pbig, O0, 0, 0, 0);
                O1 = __builtin_amdgcn_mfma_f32_16x16x32_bf16(vb, pbig, O1, 0, 0, 0);
                __builtin_amdgcn_wave_barrier();
            }
#endif
        }

        float rl = 1.f / l;
        #pragma unroll
        for (int r = 0; r < 4; r++) {
            Osm[wave * 528 + qcol * 33 + quad * 4 + r]      = O0[r] * rl;
            Osm[wave * 528 + qcol * 33 + 16 + quad * 4 + r] = O1[r] * rl;
        }
        __builtin_amdgcn_wave_barrier();
        int row = lane >> 2, dseg = (lane & 3) * 8;
        int q_out = qt * 16 + row;
        if (q_out < N) {
            bf16x8 ov;
            #pragma unroll
            for (int e = 0; e < 8; e++) ov.v[e] = f2b(Osm[wave * 528 + row * 33 + dseg + e]);
            *reinterpret_cast<bf16x8*>(out + ((size_t)(w * N + q_out)) * 256 + h * 32 + dseg) = ov;
        }
        __builtin_amdgcn_wave_barrier();
    }
}

// ---------------------------------------------------------------- xcat build: [w][520][256] = ct_window(ct0) || (x + pe)
__global__ __launch_bounds__(256) void xcatbuild_k(const float* __restrict__ x_in,
                                                   const float* __restrict__ pe,
                                                   const float* __restrict__ ct2,
                                                   float* __restrict__ xcat) {
    int row = blockIdx.x, w = row / 520, p = row - w * 520, c = threadIdx.x;
    float v;
    if (p < 8) {
        int P = w >> 4, Q = (w >> 2) & 3, R = w & 3;
        int S = p >> 2, T = (p >> 1) & 1, U = p & 1;
        int t = P * 128 + S * 64 + Q * 16 + T * 8 + R * 2 + U;
        v = ct2[(size_t)t * 256 + c];
    } else {
        int t = p - 8;
        v = x_in[((size_t)w * 512 + t) * 256 + c] + pe[(size_t)t * 256 + c];
    }
    xcat[(size_t)row * 256 + c] = v;
}

// ---------------------------------------------------------------- output split (f32 out)
__global__ __launch_bounds__(256) void outbuild_k(const float* __restrict__ xcat,
                                                  float* __restrict__ out) {
    int row = blockIdx.x, w = row / 520, p = row - w * 520, c = threadIdx.x;
    float v = xcat[(size_t)row * 256 + c];
    if (p >= 8) out[((size_t)(w * 512) + (p - 8)) * 256 + c] = v;
    else        out[(size_t)8388608 + ((size_t)(w * 8) + p) * 256 + c] = v;
}

// ----------------------------------------------------------------
extern "C" void kernel_launch(void* const* d_in, const int* in_sizes, int n_in,
                              void* d_out, int out_size, void* d_ws, size_t ws_size,
                              hipStream_t stream) {
    const float* x          = (const float*)d_in[0];
    const float* ct         = (const float*)d_in[1];
    const float* pe_w1      = (const float*)d_in[2];
    const float* pe_b1      = (const float*)d_in[3];
    const float* pe_w2      = (const float*)d_in[4];
    const float* hpe_w1     = (const float*)d_in[5];
    const float* hpe_b1     = (const float*)d_in[6];
    const float* hpe_w2     = (const float*)d_in[7];
    const float* hat_n1_g   = (const float*)d_in[8];
    const float* hat_n1_b   = (const float*)d_in[9];
    const float* hat_qkv_w  = (const float*)d_in[10];
    const float* hat_qkv_b  = (const float*)d_in[11];
    const float* hat_proj_w = (const float*)d_in[12];
    const float* hat_proj_b = (const float*)d_in[13];
    const float* hat_cpb_w1 = (const float*)d_in[14];
    const float* hat_cpb_b1 = (const float*)d_in[15];
    const float* hat_cpb_w2 = (const float*)d_in[16];
    const float* hat_n2_g   = (const float*)d_in[17];
    const float* hat_n2_b   = (const float*)d_in[18];
    const float* hat_fc1_w  = (const float*)d_in[19];
    const float* hat_fc1_b  = (const float*)d_in[20];
    const float* hat_fc2_w  = (const float*)d_in[21];
    const float* hat_fc2_b  = (const float*)d_in[22];
    const float* n1_g       = (const float*)d_in[23];
    const float* n1_b       = (const float*)d_in[24];
    const float* qkv_w      = (const float*)d_in[25];
    const float* qkv_b      = (const float*)d_in[26];
    const float* proj_w     = (const float*)d_in[27];
    const float* proj_b     = (const float*)d_in[28];
    const float* cpb_w1     = (const float*)d_in[29];
    const float* cpb_b1     = (const float*)d_in[30];
    const float* cpb_w2     = (const float*)d_in[31];
    const float* n2_g       = (const float*)d_in[32];
    const float* n2_b       = (const float*)d_in[33];
    const float* fc1_w      = (const float*)d_in[34];
    const float* fc1_b      = (const float*)d_in[35];
    const float* fc2_w      = (const float*)d_in[36];
    const float* fc2_b      = (const float*)d_in[37];
    (void)ws_size; (void)in_sizes; (void)n_in; (void)out_size;

    // ---- workspace layout (~69 MiB peak)
    char* base = (char*)d_ws;
    size_t off = 0;
    auto alloc = [&](size_t bytes) -> void* {
        void* p = base + off;
        off += (bytes + 255) & ~(size_t)255;
        return p;
    };
    // persistent (~13 MB)
    float* pe        = (float*)alloc(512 * 256 * 4);
    float* hpe       = (float*)alloc(512 * 256 * 4);
    float* tab_hat   = (float*)alloc(3375 * 8 * 4);
    float* tab2      = (float*)alloc(3375 * 8 * 4);
    float* biasT2    = (float*)alloc((size_t)8 * 512 * 512 * 4);
    float* ct0       = (float*)alloc(512 * 256 * 4);
    bf16* wb_hqkv  = (bf16*)alloc(768 * 256 * 2);
    bf16* wb_hproj = (bf16*)alloc(256 * 256 * 2);
    bf16* wb_hfc1  = (bf16*)alloc(1024 * 256 * 2);
    bf16* wb_hfc2  = (bf16*)alloc(256 * 1024 * 2);
    bf16* wb_qkv   = (bf16*)alloc(768 * 256 * 2);
    bf16* wb_proj  = (bf16*)alloc(256 * 256 * 2);
    bf16* wb_fc1   = (bf16*)alloc(1024 * 256 * 2);
    bf16* wb_fc2   = (bf16*)alloc(256 * 1024 * 2);
    size_t zstart = off;
    // hat-phase temporaries — dead before xcat is written
    float* biasT_hat = (float*)alloc((size_t)8 * 512 * 512 * 4);
    bf16*  hct_ln    = (bf16*)alloc(512 * 256 * 2);
    bf16*  hqkv      = (bf16*)alloc(512 * 768 * 2);
    bf16*  hat_attn  = (bf16*)alloc(512 * 256 * 2);
    bf16*  hat_hid   = (bf16*)alloc(512 * 1024 * 2);
    // main-phase buffers overlay hat temporaries
    off = zstart;
    float* xcat      = (float*)alloc((size_t)64 * 520 * 256 * 4);   // 34.1 MB
    bf16*  xln_slab  = (bf16*)alloc((size_t)8320 * 256 * 2);        // 4.3 MB
    char*  region_qa = (char*)alloc((size_t)8320 * 768 * 2 + (size_t)8320 * 256 * 2); // 17.0 MB
    bf16*  qkv_slab  = (bf16*)region_qa;
    bf16*  attn_slab = (bf16*)(region_qa + (size_t)8320 * 768 * 2);
    bf16*  hidden    = (bf16*)region_qa;                            // aliases qkv+attn in MLP phase

    // weight conversion f32 -> bf16 (one launch)
    wcvt8_k<<<dim3(1024, 8), 256, 0, stream>>>(hat_qkv_w, hat_proj_w, hat_fc1_w, hat_fc2_w,
                                               qkv_w, proj_w, fc1_w, fc2_w,
                                               wb_hqkv, wb_hproj, wb_hfc1, wb_hfc2,
                                               wb_qkv, wb_proj, wb_fc1, wb_fc2);

    // small tables (merged launches)
    posmlp_k<<<dim3(512, 2), 256, 0, stream>>>(pe_w1, pe_b1, pe_w2, pe, hpe_w1, hpe_b1, hpe_w2, hpe);
    cpbtab_k<<<dim3(3375, 2), 512, 0, stream>>>(hat_cpb_w1, hat_cpb_b1, hat_cpb_w2, tab_hat,
                                                cpb_w1, cpb_b1, cpb_w2, tab2);
    biasbuild_k<<<dim3(8192, 2), 256, 0, stream>>>(tab_hat, biasT_hat, tab2, biasT2);

    // hat branch (512 tokens, 1 window, glob=0)
    ct0build_k<<<512, 256, 0, stream>>>(ct, hpe, ct0);
    ln_k<<<512, 256, 0, stream>>>(ct0, hat_n1_g, hat_n1_b, hct_ln);
    gemm_k<0><<<dim3(6, 4), 256, 0, stream>>>(hct_ln, wb_hqkv, hat_qkv_b, 512, 768, 256, nullptr, hqkv);
    flash_k<<<dim3(8, 4), 512, 0, stream>>>(hqkv, biasT_hat, hat_attn, 512, 0);
    gemm_k<2><<<dim3(2, 4), 256, 0, stream>>>(hat_attn, wb_hproj, hat_proj_b, 512, 256, 256, ct0, nullptr);
    ln_k<<<512, 256, 0, stream>>>(ct0, hat_n2_g, hat_n2_b, hct_ln);
    gemm_k<1><<<dim3(8, 4), 256, 0, stream>>>(hct_ln, wb_hfc1, hat_fc1_b, 512, 1024, 256, nullptr, hat_hid);
    gemm_k<2><<<dim3(2, 4), 256, 0, stream>>>(hat_hid, wb_hfc2, hat_fc2_b, 512, 256, 1024, ct0, nullptr);

    // concat: ct_window(ct0) || x + pe   (hat temporaries dead now)
    xcatbuild_k<<<33280, 256, 0, stream>>>(x, pe, ct0, xcat);

    // main branch: attention in 4 slabs of 16 windows (8320 rows)
    for (int s = 0; s < 4; s++) {
        float* xc = xcat + (size_t)s * 8320 * 256;
        ln_k<<<8320, 256, 0, stream>>>(xc, n1_g, n1_b, xln_slab);
        gemm_k<0><<<dim3(6, 65), 256, 0, stream>>>(xln_slab, wb_qkv, qkv_b, 8320, 768, 256, nullptr, qkv_slab);
        flash_k<<<dim3(128, 5), 512, 0, stream>>>(qkv_slab, biasT2, attn_slab, 520, 8);
        gemm_k<2><<<dim3(2, 65), 256, 0, stream>>>(attn_slab, wb_proj, proj_b, 8320, 256, 256, xc, nullptr);
    }
    // MLP in 4 slabs (hidden aliases dead qkv/attn region)
    for (int s = 0; s < 4; s++) {
        float* xc = xcat + (size_t)s * 8320 * 256;
        ln_k<<<8320, 256, 0, stream>>>(xc, n2_g, n2_b, xln_slab);
        gemm_k<1><<<dim3(8, 65), 256, 0, stream>>>(xln_slab, wb_fc1, fc1_b, 8320, 1024, 256, nullptr, hidden);
        gemm_k<2><<<dim3(2, 65), 256, 0, stream>>>(hidden, wb_fc2, fc2_b, 8320, 256, 1024, xc, nullptr);
    }

    outbuild_k<<<33280, 256, 0, stream>>>(xcat, (float*)d_out);
}

// Round 7
// 828.773 us; speedup vs baseline: 1.1733x; 1.1733x over previous
//
#include <hip/hip_runtime.h>
#include <hip/hip_bf16.h>
#include <math.h>

typedef __hip_bfloat16 bf16;

#define SCALE_QK 0.17677669529663687f  /* 32^-0.5 */

__device__ __forceinline__ float b2f(bf16 v){ return __bfloat162float(v); }
__device__ __forceinline__ bf16  f2b(float v){ return __float2bfloat16(v); }
__device__ __forceinline__ short bfs(float x){ bf16 b = f2b(x); short s; __builtin_memcpy(&s, &b, 2); return s; }

struct __align__(16) bf16x8 { bf16 v[8]; };

typedef __attribute__((ext_vector_type(8))) short sh8;
typedef __attribute__((ext_vector_type(4))) short sh4;
typedef __attribute__((ext_vector_type(4))) float f4;

#if defined(__has_builtin)
#if __has_builtin(__builtin_amdgcn_mfma_f32_16x16x16bf16_1k)
#define HAS_MFMA16 1
#else
#define HAS_MFMA16 0
#endif
#else
#define HAS_MFMA16 0
#endif

// ---------------------------------------------------------------- 10 weight tensors f32 -> bf16, one launch
__global__ __launch_bounds__(256) void wcvt10_k(const float* s0, const float* s1, const float* s2, const float* s3,
                                                const float* s4, const float* s5, const float* s6, const float* s7,
                                                const float* s8, const float* s9,
                                                bf16* d0, bf16* d1, bf16* d2, bf16* d3, bf16* d4,
                                                bf16* d5, bf16* d6, bf16* d7, bf16* d8, bf16* d9) {
    const int sizes[10] = {196608, 65536, 262144, 262144, 196608, 65536, 262144, 262144, 131072, 131072};
    int which = blockIdx.y;
    const float* s; bf16* d;
    switch (which) {
        case 0: s = s0; d = d0; break;  case 1: s = s1; d = d1; break;
        case 2: s = s2; d = d2; break;  case 3: s = s3; d = d3; break;
        case 4: s = s4; d = d4; break;  case 5: s = s5; d = d5; break;
        case 6: s = s6; d = d6; break;  case 7: s = s7; d = d7; break;
        case 8: s = s8; d = d8; break;  default: s = s9; d = d9; break;
    }
    int i = blockIdx.x * 256 + threadIdx.x;
    if (i < sizes[which]) d[i] = f2b(s[i]);
}

// ---------------------------------------------------------------- pos-emb hidden build (both tables)
// hid[y][t][j] = relu(coord(t) . w1[j] + b1[j]) as bf16, row stride 512
__global__ __launch_bounds__(256) void hidbuild_k(const float* __restrict__ w1a, const float* __restrict__ b1a,
                                                  const float* __restrict__ w1b, const float* __restrict__ b1b,
                                                  bf16* __restrict__ hidA, bf16* __restrict__ hidB) {
    const float* w1 = blockIdx.y ? w1b : w1a;
    const float* b1 = blockIdx.y ? b1b : b1a;
    bf16* hid       = blockIdx.y ? hidB : hidA;
    int t = blockIdx.x, tid = threadIdx.x;
    int i = t >> 6, j = (t >> 3) & 7, k = t & 7;
    float c0 = (i - 4) * 0.25f, c1 = (j - 4) * 0.25f, c2 = (k - 4) * 0.25f;
    #pragma unroll
    for (int rep = 0; rep < 2; rep++) {
        int jj = tid + rep * 256;
        float h = c0 * w1[jj*3+0] + c1 * w1[jj*3+1] + c2 * w1[jj*3+2] + b1[jj];
        hid[(size_t)t * 512 + jj] = f2b(fmaxf(h, 0.f));
    }
}

// ---------------------------------------------------------------- CPB table MLP (both tables, y picks)
__device__ __forceinline__ float cpb_coord(int idx) {
    float v = (idx - 7) * (8.0f / 7.0f);
    return copysignf(log2f(fabsf(v) + 1.0f) * (1.0f / 3.0f), v);
}
__global__ __launch_bounds__(512) void cpbtab_k(const float* __restrict__ w1a, const float* __restrict__ b1a,
                                                const float* __restrict__ w2a, float* __restrict__ taba,
                                                const float* __restrict__ w1b, const float* __restrict__ b1b,
                                                const float* __restrict__ w2b, float* __restrict__ tabb) {
    const float* w1 = blockIdx.y ? w1b : w1a;
    const float* b1 = blockIdx.y ? b1b : b1a;
    const float* w2 = blockIdx.y ? w2b : w2a;
    float* tab      = blockIdx.y ? tabb : taba;
    int t = blockIdx.x, tid = threadIdx.x;
    __shared__ float hid[512];
    int i = t / 225, r = t - i * 225, j = r / 15, k = r - j * 15;
    float x0 = cpb_coord(i), x1 = cpb_coord(j), x2 = cpb_coord(k);
    float h = x0 * w1[tid*3+0] + x1 * w1[tid*3+1] + x2 * w1[tid*3+2] + b1[tid];
    hid[tid] = fmaxf(h, 0.f);
    __syncthreads();
    int h8 = tid >> 6, lane = tid & 63;
    float p = 0.f;
    for (int jj = lane; jj < 512; jj += 64) p += hid[jj] * w2[h8*512 + jj];
    for (int off = 32; off; off >>= 1) p += __shfl_down(p, off);
    if (lane == 0) tab[t * 8 + h8] = p;
}

// ---------------------------------------------------------------- bias materialize (both tables), biasT[h][k][q]
__global__ __launch_bounds__(256) void biasbuild_k(const float* __restrict__ taba, float* __restrict__ biasTa,
                                                   const float* __restrict__ tabb, float* __restrict__ biasTb) {
    const float* tab = blockIdx.y ? tabb : taba;
    float* biasT     = blockIdx.y ? biasTb : biasTa;
    int idx = blockIdx.x * 256 + threadIdx.x;      // 8*512*512 total
    int h = idx >> 18, rem = idx & 262143;
    int kq = rem >> 9, p = rem & 511;              // kq = key token, p = query token
    int px = p >> 6, py = (p >> 3) & 7, pz = p & 7;
    int qx = kq >> 6, qy = (kq >> 3) & 7, qz = kq & 7;
    int tidx = ((px - qx + 7) * 15 + (py - qy + 7)) * 15 + (pz - qz + 7);
    float v = tab[tidx * 8 + h];
    biasT[idx] = 16.f / (1.f + __expf(-v));
}

// ---------------------------------------------------------------- ct dewindow + hpe (f32)
__global__ __launch_bounds__(256) void ct0build_k(const float* __restrict__ ct_in,
                                                  const float* __restrict__ hpe,
                                                  float* __restrict__ ct0) {
    int u = blockIdx.x, c = threadIdx.x;
    int a = u >> 7, cc = (u >> 5) & 3, e = (u >> 4) & 1, b = (u >> 2) & 3, d = (u >> 1) & 1, f = u & 1;
    int t = a * 128 + b * 32 + cc * 8 + d * 4 + e * 2 + f;
    ct0[(size_t)u * 256 + c] = ct_in[(size_t)t * 256 + c] + hpe[(size_t)u * 256 + c];
}

// ---------------------------------------------------------------- LayerNorm f32 -> bf16
__global__ __launch_bounds__(256) void ln_k(const float* __restrict__ in,
                                            const float* __restrict__ g,
                                            const float* __restrict__ b,
                                            bf16* __restrict__ out) {
    int row = blockIdx.x, c = threadIdx.x;
    float x = in[(size_t)row * 256 + c];
    float s = x, s2 = x * x;
    for (int off = 32; off; off >>= 1) { s += __shfl_down(s, off); s2 += __shfl_down(s2, off); }
    __shared__ float red[8];
    int wid = c >> 6, lane = c & 63;
    if (lane == 0) { red[wid] = s; red[wid + 4] = s2; }
    __syncthreads();
    if (c == 0) { red[0] = red[0] + red[1] + red[2] + red[3]; red[4] = red[4] + red[5] + red[6] + red[7]; }
    __syncthreads();
    float mean = red[0] * (1.f / 256.f);
    float var  = fmaxf(red[4] * (1.f / 256.f) - mean * mean, 0.f);
    float rstd = rsqrtf(var + 1e-5f);
    out[(size_t)row * 256 + c] = f2b((x - mean) * rstd * g[c] + b[c]);
}

// ---------------------------------------------------------------- MFMA GEMM (LDS-staged, round-5 proven)
// C = A(MxK,bf16) @ W(NxK,bf16)^T + bias. 128x128 tile, 4 waves = 2x2 quadrants of 64x64.
// MODE 0: bf16 store  MODE 1: bf16 GELU store  MODE 2: += f32 residual  MODE 3: f32 store (no bias)
template <int MODE>
__global__ __launch_bounds__(256) void gemm_k(const bf16* __restrict__ A,
                                              const bf16* __restrict__ W,
                                              const float* __restrict__ bias,
                                              int M, int N, int K,
                                              float* __restrict__ res,
                                              bf16* __restrict__ outb) {
    __shared__ short As[128 * 40];   // [row][k] stride 40 (pad 8)
    __shared__ short Ws[128 * 40];
    int m0 = blockIdx.y * 128, n0 = blockIdx.x * 128;
    int tid = threadIdx.x;
    int lane = tid & 63, wave = tid >> 6;
    int quad = lane >> 4, m16 = lane & 15;
    int wm = (wave & 1) * 64, wn = (wave >> 1) * 64;

    int arow = tid >> 2, acol = (tid & 3) * 8;

    f4 acc[4][4];
    #pragma unroll
    for (int i = 0; i < 4; i++)
        #pragma unroll
        for (int j = 0; j < 4; j++) acc[i][j] = (f4){0.f, 0.f, 0.f, 0.f};

    for (int k0 = 0; k0 < K; k0 += 32) {
        sh8 a0 = *reinterpret_cast<const sh8*>(A + (size_t)(m0 + arow) * K + k0 + acol);
        sh8 a1 = *reinterpret_cast<const sh8*>(A + (size_t)(m0 + arow + 64) * K + k0 + acol);
        sh8 w0 = *reinterpret_cast<const sh8*>(W + (size_t)(n0 + arow) * K + k0 + acol);
        sh8 w1 = *reinterpret_cast<const sh8*>(W + (size_t)(n0 + arow + 64) * K + k0 + acol);
        __syncthreads();
        *reinterpret_cast<sh8*>(&As[arow * 40 + acol])        = a0;
        *reinterpret_cast<sh8*>(&As[(arow + 64) * 40 + acol]) = a1;
        *reinterpret_cast<sh8*>(&Ws[arow * 40 + acol])        = w0;
        *reinterpret_cast<sh8*>(&Ws[(arow + 64) * 40 + acol]) = w1;
        __syncthreads();
        sh8 af[4], bf[4];
        #pragma unroll
        for (int mi = 0; mi < 4; mi++)
            af[mi] = *reinterpret_cast<const sh8*>(&As[(wm + mi * 16 + m16) * 40 + quad * 8]);
        #pragma unroll
        for (int ni = 0; ni < 4; ni++)
            bf[ni] = *reinterpret_cast<const sh8*>(&Ws[(wn + ni * 16 + m16) * 40 + quad * 8]);
        #pragma unroll
        for (int mi = 0; mi < 4; mi++)
            #pragma unroll
            for (int ni = 0; ni < 4; ni++)
                acc[mi][ni] = __builtin_amdgcn_mfma_f32_16x16x32_bf16(af[mi], bf[ni], acc[mi][ni], 0, 0, 0);
    }
    (void)M;

    #pragma unroll
    for (int mi = 0; mi < 4; mi++) {
        #pragma unroll
        for (int r = 0; r < 4; r++) {
            int gm = m0 + wm + mi * 16 + quad * 4 + r;
            #pragma unroll
            for (int ni = 0; ni < 4; ni++) {
                int gn = n0 + wn + ni * 16 + m16;
                float v = acc[mi][ni][r];
                if constexpr (MODE != 3) v += bias[gn];
                if constexpr (MODE == 2)      res[(size_t)gm * N + gn] += v;
                else if constexpr (MODE == 3) res[(size_t)gm * N + gn] = v;
                else if constexpr (MODE == 1) outb[(size_t)gm * N + gn] = f2b(0.5f * v * (1.0f + erff(v * 0.70710678118654752f)));
                else                          outb[(size_t)gm * N + gn] = f2b(v);
            }
        }
    }
}

// ---------------------------------------------------------------- MFMA flash attention, 32-token k-tiles
#define VSTR 548   /* shorts; 274 dwords, step 18 mod 32 -> max 2-way (free), 8B-aligned */
__global__ __launch_bounds__(512) void flash_k(const bf16* __restrict__ qkv,
                                               const float* __restrict__ biasT,
                                               bf16* __restrict__ out,
                                               int N, int glob) {
    int wh = blockIdx.x, w = wh >> 3, h = wh & 7;
    int qs = blockIdx.y, QS = gridDim.y;
    int tid = threadIdx.x;
    int lane = tid & 63, wave = tid >> 6;
    int quad = lane >> 4, qcol = lane & 15;
    const int NT32 = (N + 31) & ~31;        // 544 (main) or 512 (hat)

    __shared__ bf16  Vt[32 * VSTR];         // V^T [d][tok]
    __shared__ float Osm[8 * 528];          // per-wave O transpose scratch [16q][33]
#if !HAS_MFMA16
    __shared__ float Ps[8][16 * 17];
#endif

    for (int i = tid; i < NT32 * 4; i += 512) {
        int tok = i >> 2, seg = i & 3;
        if (tok < N) {
            const bf16* vp = qkv + ((size_t)(w * N + tok)) * 768 + 512 + h * 32 + seg * 8;
            bf16x8 vv = *reinterpret_cast<const bf16x8*>(vp);
            #pragma unroll
            for (int e = 0; e < 8; e++) Vt[(seg * 8 + e) * VSTR + tok] = vv.v[e];
        } else {
            bf16 z = f2b(0.f);
            #pragma unroll
            for (int e = 0; e < 8; e++) Vt[(seg * 8 + e) * VSTR + tok] = z;
        }
    }
    __syncthreads();

    const bf16* qbase = qkv + ((size_t)w * N) * 768 + h * 32;
    const bf16* kbase = qbase + 256;
    int nqt = (N + 15) >> 4, nkt = NT32 >> 5;

    for (int qt = wave + 8 * qs; qt < nqt; qt += 8 * QS) {
        int q_idx = qt * 16 + qcol;
        int q_rd  = (q_idx < N) ? q_idx : (N - 1);
        sh8 qfrag = *reinterpret_cast<const sh8*>(qbase + (size_t)q_rd * 768 + quad * 8);
        f4 O0 = {0.f, 0.f, 0.f, 0.f}, O1 = {0.f, 0.f, 0.f, 0.f};
        float mval = -3.0e38f, l = 0.f;

        for (int kt = 0; kt < nkt; kt++) {
            int bt = kt * 32;
            int k0 = bt + qcol, k1 = bt + 16 + qcol;
            sh8 kf0 = *reinterpret_cast<const sh8*>(kbase + (size_t)((k0 < N) ? k0 : (N - 1)) * 768 + quad * 8);
            sh8 kf1 = *reinterpret_cast<const sh8*>(kbase + (size_t)((k1 < N) ? k1 : (N - 1)) * 768 + quad * 8);
            f4 z = {0.f, 0.f, 0.f, 0.f};
            f4 s0 = __builtin_amdgcn_mfma_f32_16x16x32_bf16(kf0, qfrag, z, 0, 0, 0);
            f4 s1 = __builtin_amdgcn_mfma_f32_16x16x32_bf16(kf1, qfrag, z, 0, 0, 0);

            float vals[8];
            #pragma unroll
            for (int r = 0; r < 4; r++) {
                int tok = bt + quad * 4 + r;
                float bb = 0.f;
                if (tok < N && q_idx < N && tok >= glob && q_idx >= glob)
                    bb = biasT[((size_t)h << 18) + ((size_t)(tok - glob) << 9) + (q_idx - glob)];
                vals[r] = (tok < N) ? (s0[r] * SCALE_QK + bb) : -1e30f;
            }
            #pragma unroll
            for (int r = 0; r < 4; r++) {
                int tok = bt + 16 + quad * 4 + r;
                float bb = 0.f;
                if (tok < N && q_idx < N && tok >= glob && q_idx >= glob)
                    bb = biasT[((size_t)h << 18) + ((size_t)(tok - glob) << 9) + (q_idx - glob)];
                vals[4 + r] = (tok < N) ? (s1[r] * SCALE_QK + bb) : -1e30f;
            }
            float tmax = vals[0];
            #pragma unroll
            for (int r = 1; r < 8; r++) tmax = fmaxf(tmax, vals[r]);
            tmax = fmaxf(tmax, __shfl_xor(tmax, 16));
            tmax = fmaxf(tmax, __shfl_xor(tmax, 32));
            float mnew = fmaxf(mval, tmax);
            float alpha = __expf(mval - mnew);
            float p[8];
            #pragma unroll
            for (int r = 0; r < 8; r++) p[r] = __expf(vals[r] - mnew);
            float ps = 0.f;
            #pragma unroll
            for (int r = 0; r < 8; r++) ps += p[r];
            ps += __shfl_xor(ps, 16);
            ps += __shfl_xor(ps, 32);
            l = l * alpha + ps;
            mval = mnew;
            #pragma unroll
            for (int r = 0; r < 4; r++) { O0[r] *= alpha; O1[r] *= alpha; }

#if HAS_MFMA16
            sh4 pf0, pf1;
            #pragma unroll
            for (int r = 0; r < 4; r++) { pf0[r] = bfs(p[r]); pf1[r] = bfs(p[4 + r]); }
            sh4 v00 = *reinterpret_cast<const sh4*>(&Vt[qcol * VSTR + bt + quad * 4]);
            sh4 v10 = *reinterpret_cast<const sh4*>(&Vt[qcol * VSTR + bt + 16 + quad * 4]);
            sh4 v01 = *reinterpret_cast<const sh4*>(&Vt[(qcol + 16) * VSTR + bt + quad * 4]);
            sh4 v11 = *reinterpret_cast<const sh4*>(&Vt[(qcol + 16) * VSTR + bt + 16 + quad * 4]);
            O0 = __builtin_amdgcn_mfma_f32_16x16x16bf16_1k(v00, pf0, O0, 0, 0, 0);
            O0 = __builtin_amdgcn_mfma_f32_16x16x16bf16_1k(v10, pf1, O0, 0, 0, 0);
            O1 = __builtin_amdgcn_mfma_f32_16x16x16bf16_1k(v01, pf0, O1, 0, 0, 0);
            O1 = __builtin_amdgcn_mfma_f32_16x16x16bf16_1k(v11, pf1, O1, 0, 0, 0);
#else
            for (int half = 0; half < 2; half++) {
                #pragma unroll
                for (int r = 0; r < 4; r++) Ps[wave][(quad * 4 + r) * 17 + qcol] = p[half * 4 + r];
                __builtin_amdgcn_wave_barrier();
                sh8 pbig, va, vb;
                #pragma unroll
                for (int j = 0; j < 8; j++) {
                    int tl = quad * 8 + j;
                    float pv = (quad < 2) ? Ps[wave][tl * 17 + qcol] : 0.f;
                    pbig[j] = bfs(pv);
                    bf16 a0 = (quad < 2) ? Vt[qcol * VSTR + bt + half * 16 + tl] : f2b(0.f);
                    bf16 a1 = (quad < 2) ? Vt[(qcol + 16) * VSTR + bt + half * 16 + tl] : f2b(0.f);
                    short t0, t1;
                    __builtin_memcpy(&t0, &a0, 2); __builtin_memcpy(&t1, &a1, 2);
                    va[j] = t0; vb[j] = t1;
                }
                O0 = __builtin_amdgcn_mfma_f32_16x16x32_bf16(va, pbig, O0, 0, 0, 0);
                O1 = __builtin_amdgcn_mfma_f32_16x16x32_bf16(vb, pbig, O1, 0, 0, 0);
                __builtin_amdgcn_wave_barrier();
            }
#endif
        }

        float rl = 1.f / l;
        #pragma unroll
        for (int r = 0; r < 4; r++) {
            Osm[wave * 528 + qcol * 33 + quad * 4 + r]      = O0[r] * rl;
            Osm[wave * 528 + qcol * 33 + 16 + quad * 4 + r] = O1[r] * rl;
        }
        __builtin_amdgcn_wave_barrier();
        int row = lane >> 2, dseg = (lane & 3) * 8;
        int q_out = qt * 16 + row;
        if (q_out < N) {
            bf16x8 ov;
            #pragma unroll
            for (int e = 0; e < 8; e++) ov.v[e] = f2b(Osm[wave * 528 + row * 33 + dseg + e]);
            *reinterpret_cast<bf16x8*>(out + ((size_t)(w * N + q_out)) * 256 + h * 32 + dseg) = ov;
        }
        __builtin_amdgcn_wave_barrier();
    }
}

// ---------------------------------------------------------------- xcat build: [w][520][256] = ct_window(ct0) || (x + pe)
__global__ __launch_bounds__(256) void xcatbuild_k(const float* __restrict__ x_in,
                                                   const float* __restrict__ pe,
                                                   const float* __restrict__ ct2,
                                                   float* __restrict__ xcat) {
    int row = blockIdx.x, w = row / 520, p = row - w * 520, c = threadIdx.x;
    float v;
    if (p < 8) {
        int P = w >> 4, Q = (w >> 2) & 3, R = w & 3;
        int S = p >> 2, T = (p >> 1) & 1, U = p & 1;
        int t = P * 128 + S * 64 + Q * 16 + T * 8 + R * 2 + U;
        v = ct2[(size_t)t * 256 + c];
    } else {
        int t = p - 8;
        v = x_in[((size_t)w * 512 + t) * 256 + c] + pe[(size_t)t * 256 + c];
    }
    xcat[(size_t)row * 256 + c] = v;
}

// ---------------------------------------------------------------- output split (f32 out)
__global__ __launch_bounds__(256) void outbuild_k(const float* __restrict__ xcat,
                                                  float* __restrict__ out) {
    int row = blockIdx.x, w = row / 520, p = row - w * 520, c = threadIdx.x;
    float v = xcat[(size_t)row * 256 + c];
    if (p >= 8) out[((size_t)(w * 512) + (p - 8)) * 256 + c] = v;
    else        out[(size_t)8388608 + ((size_t)(w * 8) + p) * 256 + c] = v;
}

// ----------------------------------------------------------------
extern "C" void kernel_launch(void* const* d_in, const int* in_sizes, int n_in,
                              void* d_out, int out_size, void* d_ws, size_t ws_size,
                              hipStream_t stream) {
    const float* x          = (const float*)d_in[0];
    const float* ct         = (const float*)d_in[1];
    const float* pe_w1      = (const float*)d_in[2];
    const float* pe_b1      = (const float*)d_in[3];
    const float* pe_w2      = (const float*)d_in[4];
    const float* hpe_w1     = (const float*)d_in[5];
    const float* hpe_b1     = (const float*)d_in[6];
    const float* hpe_w2     = (const float*)d_in[7];
    const float* hat_n1_g   = (const float*)d_in[8];
    const float* hat_n1_b   = (const float*)d_in[9];
    const float* hat_qkv_w  = (const float*)d_in[10];
    const float* hat_qkv_b  = (const float*)d_in[11];
    const float* hat_proj_w = (const float*)d_in[12];
    const float* hat_proj_b = (const float*)d_in[13];
    const float* hat_cpb_w1 = (const float*)d_in[14];
    const float* hat_cpb_b1 = (const float*)d_in[15];
    const float* hat_cpb_w2 = (const float*)d_in[16];
    const float* hat_n2_g   = (const float*)d_in[17];
    const float* hat_n2_b   = (const float*)d_in[18];
    const float* hat_fc1_w  = (const float*)d_in[19];
    const float* hat_fc1_b  = (const float*)d_in[20];
    const float* hat_fc2_w  = (const float*)d_in[21];
    const float* hat_fc2_b  = (const float*)d_in[22];
    const float* n1_g       = (const float*)d_in[23];
    const float* n1_b       = (const float*)d_in[24];
    const float* qkv_w      = (const float*)d_in[25];
    const float* qkv_b      = (const float*)d_in[26];
    const float* proj_w     = (const float*)d_in[27];
    const float* proj_b     = (const float*)d_in[28];
    const float* cpb_w1     = (const float*)d_in[29];
    const float* cpb_b1     = (const float*)d_in[30];
    const float* cpb_w2     = (const float*)d_in[31];
    const float* n2_g       = (const float*)d_in[32];
    const float* n2_b       = (const float*)d_in[33];
    const float* fc1_w      = (const float*)d_in[34];
    const float* fc1_b      = (const float*)d_in[35];
    const float* fc2_w      = (const float*)d_in[36];
    const float* fc2_b      = (const float*)d_in[37];
    (void)ws_size; (void)in_sizes; (void)n_in; (void)out_size;

    // ---- workspace layout (~70 MiB peak)
    char* base = (char*)d_ws;
    size_t off = 0;
    auto alloc = [&](size_t bytes) -> void* {
        void* p = base + off;
        off += (bytes + 255) & ~(size_t)255;
        return p;
    };
    // persistent (~14 MB)
    float* pe        = (float*)alloc(512 * 256 * 4);
    float* hpe       = (float*)alloc(512 * 256 * 4);
    float* tab_hat   = (float*)alloc(3375 * 8 * 4);
    float* tab2      = (float*)alloc(3375 * 8 * 4);
    float* biasT2    = (float*)alloc((size_t)8 * 512 * 512 * 4);
    float* ct0       = (float*)alloc(512 * 256 * 4);
    bf16* wb_hqkv  = (bf16*)alloc(768 * 256 * 2);
    bf16* wb_hproj = (bf16*)alloc(256 * 256 * 2);
    bf16* wb_hfc1  = (bf16*)alloc(1024 * 256 * 2);
    bf16* wb_hfc2  = (bf16*)alloc(256 * 1024 * 2);
    bf16* wb_qkv   = (bf16*)alloc(768 * 256 * 2);
    bf16* wb_proj  = (bf16*)alloc(256 * 256 * 2);
    bf16* wb_fc1   = (bf16*)alloc(1024 * 256 * 2);
    bf16* wb_fc2   = (bf16*)alloc(256 * 1024 * 2);
    bf16* wb_pew2  = (bf16*)alloc(256 * 512 * 2);
    bf16* wb_hpew2 = (bf16*)alloc(256 * 512 * 2);
    size_t zstart = off;
    // phase-1 temporaries overlay region: hid buffers die before biasbuild writes biasT_hat
    bf16*  hidA      = (bf16*)alloc(512 * 512 * 2);
    bf16*  hidB      = (bf16*)alloc(512 * 512 * 2);
    off = zstart;
    // hat-phase temporaries — dead before xcat is written
    float* biasT_hat = (float*)alloc((size_t)8 * 512 * 512 * 4);
    bf16*  hct_ln    = (bf16*)alloc(512 * 256 * 2);
    bf16*  hqkv      = (bf16*)alloc(512 * 768 * 2);
    bf16*  hat_attn  = (bf16*)alloc(512 * 256 * 2);
    bf16*  hat_hid   = (bf16*)alloc(512 * 1024 * 2);
    // main-phase buffers overlay hat temporaries
    off = zstart;
    float* xcat      = (float*)alloc((size_t)64 * 520 * 256 * 4);   // 34.1 MB
    bf16*  xln_slab  = (bf16*)alloc((size_t)8320 * 256 * 2);        // 4.3 MB
    char*  region_qa = (char*)alloc((size_t)8320 * 768 * 2 + (size_t)8320 * 256 * 2); // 17.0 MB
    bf16*  qkv_slab  = (bf16*)region_qa;
    bf16*  attn_slab = (bf16*)(region_qa + (size_t)8320 * 768 * 2);
    bf16*  hidden    = (bf16*)region_qa;                            // aliases qkv+attn in MLP phase

    // weight conversion f32 -> bf16 (one launch)
    wcvt10_k<<<dim3(1024, 10), 256, 0, stream>>>(hat_qkv_w, hat_proj_w, hat_fc1_w, hat_fc2_w,
                                                 qkv_w, proj_w, fc1_w, fc2_w, pe_w2, hpe_w2,
                                                 wb_hqkv, wb_hproj, wb_hfc1, wb_hfc2,
                                                 wb_qkv, wb_proj, wb_fc1, wb_fc2, wb_pew2, wb_hpew2);

    // pos-emb: hidden build + MFMA gemm (M=512,N=256,K=512, f32 store)
    hidbuild_k<<<dim3(512, 2), 256, 0, stream>>>(pe_w1, pe_b1, hpe_w1, hpe_b1, hidA, hidB);
    gemm_k<3><<<dim3(2, 4), 256, 0, stream>>>(hidA, wb_pew2,  nullptr, 512, 256, 512, pe,  nullptr);
    gemm_k<3><<<dim3(2, 4), 256, 0, stream>>>(hidB, wb_hpew2, nullptr, 512, 256, 512, hpe, nullptr);

    // CPB tables + bias materialize (hid buffers dead now; biasT_hat may overlay them)
    cpbtab_k<<<dim3(3375, 2), 512, 0, stream>>>(hat_cpb_w1, hat_cpb_b1, hat_cpb_w2, tab_hat,
                                                cpb_w1, cpb_b1, cpb_w2, tab2);
    biasbuild_k<<<dim3(8192, 2), 256, 0, stream>>>(tab_hat, biasT_hat, tab2, biasT2);

    // hat branch (512 tokens, 1 window, glob=0)
    ct0build_k<<<512, 256, 0, stream>>>(ct, hpe, ct0);
    ln_k<<<512, 256, 0, stream>>>(ct0, hat_n1_g, hat_n1_b, hct_ln);
    gemm_k<0><<<dim3(6, 4), 256, 0, stream>>>(hct_ln, wb_hqkv, hat_qkv_b, 512, 768, 256, nullptr, hqkv);
    flash_k<<<dim3(8, 4), 512, 0, stream>>>(hqkv, biasT_hat, hat_attn, 512, 0);
    gemm_k<2><<<dim3(2, 4), 256, 0, stream>>>(hat_attn, wb_hproj, hat_proj_b, 512, 256, 256, ct0, nullptr);
    ln_k<<<512, 256, 0, stream>>>(ct0, hat_n2_g, hat_n2_b, hct_ln);
    gemm_k<1><<<dim3(8, 4), 256, 0, stream>>>(hct_ln, wb_hfc1, hat_fc1_b, 512, 1024, 256, nullptr, hat_hid);
    gemm_k<2><<<dim3(2, 4), 256, 0, stream>>>(hat_hid, wb_hfc2, hat_fc2_b, 512, 256, 1024, ct0, nullptr);

    // concat: ct_window(ct0) || x + pe   (hat temporaries dead now)
    xcatbuild_k<<<33280, 256, 0, stream>>>(x, pe, ct0, xcat);

    // main branch: attention in 4 slabs of 16 windows (8320 rows)
    for (int s = 0; s < 4; s++) {
        float* xc = xcat + (size_t)s * 8320 * 256;
        ln_k<<<8320, 256, 0, stream>>>(xc, n1_g, n1_b, xln_slab);
        gemm_k<0><<<dim3(6, 65), 256, 0, stream>>>(xln_slab, wb_qkv, qkv_b, 8320, 768, 256, nullptr, qkv_slab);
        flash_k<<<dim3(128, 5), 512, 0, stream>>>(qkv_slab, biasT2, attn_slab, 520, 8);
        gemm_k<2><<<dim3(2, 65), 256, 0, stream>>>(attn_slab, wb_proj, proj_b, 8320, 256, 256, xc, nullptr);
    }
    // MLP in 4 slabs (hidden aliases dead qkv/attn region)
    for (int s = 0; s < 4; s++) {
        float* xc = xcat + (size_t)s * 8320 * 256;
        ln_k<<<8320, 256, 0, stream>>>(xc, n2_g, n2_b, xln_slab);
        gemm_k<1><<<dim3(8, 65), 256, 0, stream>>>(xln_slab, wb_fc1, fc1_b, 8320, 1024, 256, nullptr, hidden);
        gemm_k<2><<<dim3(2, 65), 256, 0, stream>>>(hidden, wb_fc2, fc2_b, 8320, 256, 1024, xc, nullptr);
    }

    outbuild_k<<<33280, 256, 0, stream>>>(xcat, (float*)d_out);
}

// Round 8
// 650.140 us; speedup vs baseline: 1.4956x; 1.2748x over previous
//
#include <hip/hip_runtime.h>
#include <hip/hip_bf16.h>
#include <math.h>

typedef __hip_bfloat16 bf16;

#define SCALE_QK 0.17677669529663687f  /* 32^-0.5 */

__device__ __forceinline__ float b2f(bf16 v){ return __bfloat162float(v); }
__device__ __forceinline__ bf16  f2b(float v){ return __float2bfloat16(v); }
__device__ __forceinline__ short bfs(float x){ bf16 b = f2b(x); short s; __builtin_memcpy(&s, &b, 2); return s; }

struct __align__(16) bf16x8 { bf16 v[8]; };

typedef __attribute__((ext_vector_type(8))) short sh8;
typedef __attribute__((ext_vector_type(4))) short sh4;
typedef __attribute__((ext_vector_type(4))) float f4;

#if defined(__has_builtin)
#if __has_builtin(__builtin_amdgcn_mfma_f32_16x16x16bf16_1k)
#define HAS_MFMA16 1
#else
#define HAS_MFMA16 0
#endif
#else
#define HAS_MFMA16 0
#endif

// ---------------------------------------------------------------- 10 weight tensors f32 -> bf16, one launch
__global__ __launch_bounds__(256) void wcvt10_k(const float* s0, const float* s1, const float* s2, const float* s3,
                                                const float* s4, const float* s5, const float* s6, const float* s7,
                                                const float* s8, const float* s9,
                                                bf16* d0, bf16* d1, bf16* d2, bf16* d3, bf16* d4,
                                                bf16* d5, bf16* d6, bf16* d7, bf16* d8, bf16* d9) {
    const int sizes[10] = {196608, 65536, 262144, 262144, 196608, 65536, 262144, 262144, 131072, 131072};
    int which = blockIdx.y;
    const float* s; bf16* d;
    switch (which) {
        case 0: s = s0; d = d0; break;  case 1: s = s1; d = d1; break;
        case 2: s = s2; d = d2; break;  case 3: s = s3; d = d3; break;
        case 4: s = s4; d = d4; break;  case 5: s = s5; d = d5; break;
        case 6: s = s6; d = d6; break;  case 7: s = s7; d = d7; break;
        case 8: s = s8; d = d8; break;  default: s = s9; d = d9; break;
    }
    int i = blockIdx.x * 256 + threadIdx.x;
    if (i < sizes[which]) d[i] = f2b(s[i]);
}

// ---------------------------------------------------------------- pos-emb hidden build (both tables)
__global__ __launch_bounds__(256) void hidbuild_k(const float* __restrict__ w1a, const float* __restrict__ b1a,
                                                  const float* __restrict__ w1b, const float* __restrict__ b1b,
                                                  bf16* __restrict__ hidA, bf16* __restrict__ hidB) {
    const float* w1 = blockIdx.y ? w1b : w1a;
    const float* b1 = blockIdx.y ? b1b : b1a;
    bf16* hid       = blockIdx.y ? hidB : hidA;
    int t = blockIdx.x, tid = threadIdx.x;
    int i = t >> 6, j = (t >> 3) & 7, k = t & 7;
    float c0 = (i - 4) * 0.25f, c1 = (j - 4) * 0.25f, c2 = (k - 4) * 0.25f;
    #pragma unroll
    for (int rep = 0; rep < 2; rep++) {
        int jj = tid + rep * 256;
        float h = c0 * w1[jj*3+0] + c1 * w1[jj*3+1] + c2 * w1[jj*3+2] + b1[jj];
        hid[(size_t)t * 512 + jj] = f2b(fmaxf(h, 0.f));
    }
}

// ---------------------------------------------------------------- CPB table MLP (both tables, y picks)
__device__ __forceinline__ float cpb_coord(int idx) {
    float v = (idx - 7) * (8.0f / 7.0f);
    return copysignf(log2f(fabsf(v) + 1.0f) * (1.0f / 3.0f), v);
}
__global__ __launch_bounds__(512) void cpbtab_k(const float* __restrict__ w1a, const float* __restrict__ b1a,
                                                const float* __restrict__ w2a, float* __restrict__ taba,
                                                const float* __restrict__ w1b, const float* __restrict__ b1b,
                                                const float* __restrict__ w2b, float* __restrict__ tabb) {
    const float* w1 = blockIdx.y ? w1b : w1a;
    const float* b1 = blockIdx.y ? b1b : b1a;
    const float* w2 = blockIdx.y ? w2b : w2a;
    float* tab      = blockIdx.y ? tabb : taba;
    int t = blockIdx.x, tid = threadIdx.x;
    __shared__ float hid[512];
    int i = t / 225, r = t - i * 225, j = r / 15, k = r - j * 15;
    float x0 = cpb_coord(i), x1 = cpb_coord(j), x2 = cpb_coord(k);
    float h = x0 * w1[tid*3+0] + x1 * w1[tid*3+1] + x2 * w1[tid*3+2] + b1[tid];
    hid[tid] = fmaxf(h, 0.f);
    __syncthreads();
    int h8 = tid >> 6, lane = tid & 63;
    float p = 0.f;
    for (int jj = lane; jj < 512; jj += 64) p += hid[jj] * w2[h8*512 + jj];
    for (int off = 32; off; off >>= 1) p += __shfl_down(p, off);
    if (lane == 0) tab[t * 8 + h8] = p;
}

// ---------------------------------------------------------------- bias materialize (both), NATURAL layout biasQ[h][q][k]
__global__ __launch_bounds__(256) void biasbuild_k(const float* __restrict__ taba, float* __restrict__ biasQa,
                                                   const float* __restrict__ tabb, float* __restrict__ biasQb) {
    const float* tab = blockIdx.y ? tabb : taba;
    float* biasQ     = blockIdx.y ? biasQb : biasQa;
    int idx = blockIdx.x * 256 + threadIdx.x;      // 8*512*512 total
    int h = idx >> 18, rem = idx & 262143;
    int q = rem >> 9, k = rem & 511;
    int qx = q >> 6, qy = (q >> 3) & 7, qz = q & 7;
    int kx = k >> 6, ky = (k >> 3) & 7, kz = k & 7;
    int tidx = ((qx - kx + 7) * 15 + (qy - ky + 7)) * 15 + (qz - kz + 7);
    float v = tab[tidx * 8 + h];
    biasQ[idx] = 16.f / (1.f + __expf(-v));
}

// ---------------------------------------------------------------- ct dewindow + hpe (f32)
__global__ __launch_bounds__(256) void ct0build_k(const float* __restrict__ ct_in,
                                                  const float* __restrict__ hpe,
                                                  float* __restrict__ ct0) {
    int u = blockIdx.x, c = threadIdx.x;
    int a = u >> 7, cc = (u >> 5) & 3, e = (u >> 4) & 1, b = (u >> 2) & 3, d = (u >> 1) & 1, f = u & 1;
    int t = a * 128 + b * 32 + cc * 8 + d * 4 + e * 2 + f;
    ct0[(size_t)u * 256 + c] = ct_in[(size_t)t * 256 + c] + hpe[(size_t)u * 256 + c];
}

// ---------------------------------------------------------------- LayerNorm f32 -> bf16
__global__ __launch_bounds__(256) void ln_k(const float* __restrict__ in,
                                            const float* __restrict__ g,
                                            const float* __restrict__ b,
                                            bf16* __restrict__ out) {
    int row = blockIdx.x, c = threadIdx.x;
    float x = in[(size_t)row * 256 + c];
    float s = x, s2 = x * x;
    for (int off = 32; off; off >>= 1) { s += __shfl_down(s, off); s2 += __shfl_down(s2, off); }
    __shared__ float red[8];
    int wid = c >> 6, lane = c & 63;
    if (lane == 0) { red[wid] = s; red[wid + 4] = s2; }
    __syncthreads();
    if (c == 0) { red[0] = red[0] + red[1] + red[2] + red[3]; red[4] = red[4] + red[5] + red[6] + red[7]; }
    __syncthreads();
    float mean = red[0] * (1.f / 256.f);
    float var  = fmaxf(red[4] * (1.f / 256.f) - mean * mean, 0.f);
    float rstd = rsqrtf(var + 1e-5f);
    out[(size_t)row * 256 + c] = f2b((x - mean) * rstd * g[c] + b[c]);
}

// ---------------------------------------------------------------- MFMA GEMM (LDS-staged, round-5 proven)
// MODE 0: bf16 store  MODE 1: bf16 GELU store  MODE 2: += f32 residual  MODE 3: f32 store (no bias)
template <int MODE>
__global__ __launch_bounds__(256) void gemm_k(const bf16* __restrict__ A,
                                              const bf16* __restrict__ W,
                                              const float* __restrict__ bias,
                                              int M, int N, int K,
                                              float* __restrict__ res,
                                              bf16* __restrict__ outb) {
    __shared__ short As[128 * 40];
    __shared__ short Ws[128 * 40];
    int m0 = blockIdx.y * 128, n0 = blockIdx.x * 128;
    int tid = threadIdx.x;
    int lane = tid & 63, wave = tid >> 6;
    int quad = lane >> 4, m16 = lane & 15;
    int wm = (wave & 1) * 64, wn = (wave >> 1) * 64;
    int arow = tid >> 2, acol = (tid & 3) * 8;

    f4 acc[4][4];
    #pragma unroll
    for (int i = 0; i < 4; i++)
        #pragma unroll
        for (int j = 0; j < 4; j++) acc[i][j] = (f4){0.f, 0.f, 0.f, 0.f};

    for (int k0 = 0; k0 < K; k0 += 32) {
        sh8 a0 = *reinterpret_cast<const sh8*>(A + (size_t)(m0 + arow) * K + k0 + acol);
        sh8 a1 = *reinterpret_cast<const sh8*>(A + (size_t)(m0 + arow + 64) * K + k0 + acol);
        sh8 w0 = *reinterpret_cast<const sh8*>(W + (size_t)(n0 + arow) * K + k0 + acol);
        sh8 w1 = *reinterpret_cast<const sh8*>(W + (size_t)(n0 + arow + 64) * K + k0 + acol);
        __syncthreads();
        *reinterpret_cast<sh8*>(&As[arow * 40 + acol])        = a0;
        *reinterpret_cast<sh8*>(&As[(arow + 64) * 40 + acol]) = a1;
        *reinterpret_cast<sh8*>(&Ws[arow * 40 + acol])        = w0;
        *reinterpret_cast<sh8*>(&Ws[(arow + 64) * 40 + acol]) = w1;
        __syncthreads();
        sh8 af[4], bf[4];
        #pragma unroll
        for (int mi = 0; mi < 4; mi++)
            af[mi] = *reinterpret_cast<const sh8*>(&As[(wm + mi * 16 + m16) * 40 + quad * 8]);
        #pragma unroll
        for (int ni = 0; ni < 4; ni++)
            bf[ni] = *reinterpret_cast<const sh8*>(&Ws[(wn + ni * 16 + m16) * 40 + quad * 8]);
        #pragma unroll
        for (int mi = 0; mi < 4; mi++)
            #pragma unroll
            for (int ni = 0; ni < 4; ni++)
                acc[mi][ni] = __builtin_amdgcn_mfma_f32_16x16x32_bf16(af[mi], bf[ni], acc[mi][ni], 0, 0, 0);
    }
    (void)M;

    #pragma unroll
    for (int mi = 0; mi < 4; mi++) {
        #pragma unroll
        for (int r = 0; r < 4; r++) {
            int gm = m0 + wm + mi * 16 + quad * 4 + r;
            #pragma unroll
            for (int ni = 0; ni < 4; ni++) {
                int gn = n0 + wn + ni * 16 + m16;
                float v = acc[mi][ni][r];
                if constexpr (MODE != 3) v += bias[gn];
                if constexpr (MODE == 2)      res[(size_t)gm * N + gn] += v;
                else if constexpr (MODE == 3) res[(size_t)gm * N + gn] = v;
                else if constexpr (MODE == 1) outb[(size_t)gm * N + gn] = f2b(0.5f * v * (1.0f + erff(v * 0.70710678118654752f)));
                else                          outb[(size_t)gm * N + gn] = f2b(v);
            }
        }
    }
}

// ---------------------------------------------------------------- MFMA flash attention, fixed-max softmax
// qkv: [win][N][768] bf16; biasQ: [8][512][512] f32 = bias[h][query][key] (natural)
// Fixed max M=24: scores structurally bounded (LN inputs, 0.02-scale W, bias<16) -> exp(s-24)
// can't overflow; softmax shift-invariant. l reduced across quads AFTER k-loop.
#define VSTR 548   /* shorts; step 18 mod 32 -> max 2-way (free), 8B-aligned */
#define FIXM 24.0f
__global__ __launch_bounds__(512) void flash_k(const bf16* __restrict__ qkv,
                                               const float* __restrict__ biasQ,
                                               bf16* __restrict__ out,
                                               int N, int glob) {
    int wh = blockIdx.x, w = wh >> 3, h = wh & 7;
    int qs = blockIdx.y, QS = gridDim.y;
    int tid = threadIdx.x;
    int lane = tid & 63, wave = tid >> 6;
    int quad = lane >> 4, qcol = lane & 15;
    const int NT32 = (N + 31) & ~31;

    __shared__ bf16  Vt[32 * VSTR];
    __shared__ float Osm[8 * 528];
#if !HAS_MFMA16
    __shared__ float Ps[8][16 * 17];
#endif

    for (int i = tid; i < NT32 * 4; i += 512) {
        int tok = i >> 2, seg = i & 3;
        if (tok < N) {
            const bf16* vp = qkv + ((size_t)(w * N + tok)) * 768 + 512 + h * 32 + seg * 8;
            bf16x8 vv = *reinterpret_cast<const bf16x8*>(vp);
            #pragma unroll
            for (int e = 0; e < 8; e++) Vt[(seg * 8 + e) * VSTR + tok] = vv.v[e];
        } else {
            bf16 z = f2b(0.f);
            #pragma unroll
            for (int e = 0; e < 8; e++) Vt[(seg * 8 + e) * VSTR + tok] = z;
        }
    }
    __syncthreads();

    const bf16* qbase = qkv + ((size_t)w * N) * 768 + h * 32;
    const bf16* kbase = qbase + 256;
    int nqt = (N + 15) >> 4, nkt = NT32 >> 5;

    for (int qt = wave + 8 * qs; qt < nqt; qt += 8 * QS) {
        int q_idx = qt * 16 + qcol;
        int q_rd  = (q_idx < N) ? q_idx : (N - 1);
        sh8 qfrag = *reinterpret_cast<const sh8*>(qbase + (size_t)q_rd * 768 + quad * 8);
        f4 O0 = {0.f, 0.f, 0.f, 0.f}, O1 = {0.f, 0.f, 0.f, 0.f};
        float l = 0.f;
        bool qb = (q_idx >= glob) && (q_idx < N);
        // brow[tok] = biasQ[h][q-glob][tok-glob]; (tok-glob) % 4 == 0 for 4-aligned groups
        const float* brow = biasQ + (((size_t)h << 9) + (size_t)(qb ? (q_idx - glob) : 0)) * 512 - glob;

        for (int kt = 0; kt < nkt; kt++) {
            int bt = kt * 32;
            int k0 = bt + qcol, k1 = bt + 16 + qcol;
            sh8 kf0 = *reinterpret_cast<const sh8*>(kbase + (size_t)((k0 < N) ? k0 : (N - 1)) * 768 + quad * 8);
            sh8 kf1 = *reinterpret_cast<const sh8*>(kbase + (size_t)((k1 < N) ? k1 : (N - 1)) * 768 + quad * 8);
            f4 z = {0.f, 0.f, 0.f, 0.f};
            f4 s0 = __builtin_amdgcn_mfma_f32_16x16x32_bf16(kf0, qfrag, z, 0, 0, 0);
            f4 s1 = __builtin_amdgcn_mfma_f32_16x16x32_bf16(kf1, qfrag, z, 0, 0, 0);

            int tg0 = bt + quad * 4, tg1 = bt + 16 + quad * 4;   // 4-aligned; never straddle glob or N
            float p[8];
            {
                f4 bb = {0.f, 0.f, 0.f, 0.f};
                if (qb && tg0 >= glob) bb = *reinterpret_cast<const f4*>(brow + tg0);
                bool valid = tg0 < N;
                #pragma unroll
                for (int r = 0; r < 4; r++)
                    p[r] = valid ? __expf(fmaf(s0[r], SCALE_QK, bb[r]) - FIXM) : 0.f;
            }
            {
                f4 bb = {0.f, 0.f, 0.f, 0.f};
                if (qb && tg1 >= glob && tg1 < N) bb = *reinterpret_cast<const f4*>(brow + tg1);
                bool valid = tg1 < N;
                #pragma unroll
                for (int r = 0; r < 4; r++)
                    p[4 + r] = valid ? __expf(fmaf(s1[r], SCALE_QK, bb[r]) - FIXM) : 0.f;
            }
            #pragma unroll
            for (int r = 0; r < 8; r++) l += p[r];

#if HAS_MFMA16
            sh4 pf0, pf1;
            #pragma unroll
            for (int r = 0; r < 4; r++) { pf0[r] = bfs(p[r]); pf1[r] = bfs(p[4 + r]); }
            sh4 v00 = *reinterpret_cast<const sh4*>(&Vt[qcol * VSTR + bt + quad * 4]);
            sh4 v10 = *reinterpret_cast<const sh4*>(&Vt[qcol * VSTR + bt + 16 + quad * 4]);
            sh4 v01 = *reinterpret_cast<const sh4*>(&Vt[(qcol + 16) * VSTR + bt + quad * 4]);
            sh4 v11 = *reinterpret_cast<const sh4*>(&Vt[(qcol + 16) * VSTR + bt + 16 + quad * 4]);
            O0 = __builtin_amdgcn_mfma_f32_16x16x16bf16_1k(v00, pf0, O0, 0, 0, 0);
            O0 = __builtin_amdgcn_mfma_f32_16x16x16bf16_1k(v10, pf1, O0, 0, 0, 0);
            O1 = __builtin_amdgcn_mfma_f32_16x16x16bf16_1k(v01, pf0, O1, 0, 0, 0);
            O1 = __builtin_amdgcn_mfma_f32_16x16x16bf16_1k(v11, pf1, O1, 0, 0, 0);
#else
            for (int half = 0; half < 2; half++) {
                #pragma unroll
                for (int r = 0; r < 4; r++) Ps[wave][(quad * 4 + r) * 17 + qcol] = p[half * 4 + r];
                __builtin_amdgcn_wave_barrier();
                sh8 pbig, va, vb;
                #pragma unroll
                for (int j = 0; j < 8; j++) {
                    int tl = quad * 8 + j;
                    float pv = (quad < 2) ? Ps[wave][tl * 17 + qcol] : 0.f;
                    pbig[j] = bfs(pv);
                    bf16 a0 = (quad < 2) ? Vt[qcol * VSTR + bt + half * 16 + tl] : f2b(0.f);
                    bf16 a1 = (quad < 2) ? Vt[(qcol + 16) * VSTR + bt + half * 16 + tl] : f2b(0.f);
                    short t0, t1;
                    __builtin_memcpy(&t0, &a0, 2); __builtin_memcpy(&t1, &a1, 2);
                    va[j] = t0; vb[j] = t1;
                }
                O0 = __builtin_amdgcn_mfma_f32_16x16x32_bf16(va, pbig, O0, 0, 0, 0);
                O1 = __builtin_amdgcn_mfma_f32_16x16x32_bf16(vb, pbig, O1, 0, 0, 0);
                __builtin_amdgcn_wave_barrier();
            }
#endif
        }

        l += __shfl_xor(l, 16);
        l += __shfl_xor(l, 32);
        float rl = 1.f / l;
        #pragma unroll
        for (int r = 0; r < 4; r++) {
            Osm[wave * 528 + qcol * 33 + quad * 4 + r]      = O0[r] * rl;
            Osm[wave * 528 + qcol * 33 + 16 + quad * 4 + r] = O1[r] * rl;
        }
        __builtin_amdgcn_wave_barrier();
        int row = lane >> 2, dseg = (lane & 3) * 8;
        int q_out = qt * 16 + row;
        if (q_out < N) {
            bf16x8 ov;
            #pragma unroll
            for (int e = 0; e < 8; e++) ov.v[e] = f2b(Osm[wave * 528 + row * 33 + dseg + e]);
            *reinterpret_cast<bf16x8*>(out + ((size_t)(w * N + q_out)) * 256 + h * 32 + dseg) = ov;
        }
        __builtin_amdgcn_wave_barrier();
    }
}

// ---------------------------------------------------------------- xcat build: [w][520][256] = ct_window(ct0) || (x + pe)
__global__ __launch_bounds__(256) void xcatbuild_k(const float* __restrict__ x_in,
                                                   const float* __restrict__ pe,
                                                   const float* __restrict__ ct2,
                                                   float* __restrict__ xcat) {
    int row = blockIdx.x, w = row / 520, p = row - w * 520, c = threadIdx.x;
    float v;
    if (p < 8) {
        int P = w >> 4, Q = (w >> 2) & 3, R = w & 3;
        int S = p >> 2, T = (p >> 1) & 1, U = p & 1;
        int t = P * 128 + S * 64 + Q * 16 + T * 8 + R * 2 + U;
        v = ct2[(size_t)t * 256 + c];
    } else {
        int t = p - 8;
        v = x_in[((size_t)w * 512 + t) * 256 + c] + pe[(size_t)t * 256 + c];
    }
    xcat[(size_t)row * 256 + c] = v;
}

// ---------------------------------------------------------------- output split (f32 out)
__global__ __launch_bounds__(256) void outbuild_k(const float* __restrict__ xcat,
                                                  float* __restrict__ out) {
    int row = blockIdx.x, w = row / 520, p = row - w * 520, c = threadIdx.x;
    float v = xcat[(size_t)row * 256 + c];
    if (p >= 8) out[((size_t)(w * 512) + (p - 8)) * 256 + c] = v;
    else        out[(size_t)8388608 + ((size_t)(w * 8) + p) * 256 + c] = v;
}

// ----------------------------------------------------------------
extern "C" void kernel_launch(void* const* d_in, const int* in_sizes, int n_in,
                              void* d_out, int out_size, void* d_ws, size_t ws_size,
                              hipStream_t stream) {
    const float* x          = (const float*)d_in[0];
    const float* ct         = (const float*)d_in[1];
    const float* pe_w1      = (const float*)d_in[2];
    const float* pe_b1      = (const float*)d_in[3];
    const float* pe_w2      = (const float*)d_in[4];
    const float* hpe_w1     = (const float*)d_in[5];
    const float* hpe_b1     = (const float*)d_in[6];
    const float* hpe_w2     = (const float*)d_in[7];
    const float* hat_n1_g   = (const float*)d_in[8];
    const float* hat_n1_b   = (const float*)d_in[9];
    const float* hat_qkv_w  = (const float*)d_in[10];
    const float* hat_qkv_b  = (const float*)d_in[11];
    const float* hat_proj_w = (const float*)d_in[12];
    const float* hat_proj_b = (const float*)d_in[13];
    const float* hat_cpb_w1 = (const float*)d_in[14];
    const float* hat_cpb_b1 = (const float*)d_in[15];
    const float* hat_cpb_w2 = (const float*)d_in[16];
    const float* hat_n2_g   = (const float*)d_in[17];
    const float* hat_n2_b   = (const float*)d_in[18];
    const float* hat_fc1_w  = (const float*)d_in[19];
    const float* hat_fc1_b  = (const float*)d_in[20];
    const float* hat_fc2_w  = (const float*)d_in[21];
    const float* hat_fc2_b  = (const float*)d_in[22];
    const float* n1_g       = (const float*)d_in[23];
    const float* n1_b       = (const float*)d_in[24];
    const float* qkv_w      = (const float*)d_in[25];
    const float* qkv_b      = (const float*)d_in[26];
    const float* proj_w     = (const float*)d_in[27];
    const float* proj_b     = (const float*)d_in[28];
    const float* cpb_w1     = (const float*)d_in[29];
    const float* cpb_b1     = (const float*)d_in[30];
    const float* cpb_w2     = (const float*)d_in[31];
    const float* n2_g       = (const float*)d_in[32];
    const float* n2_b       = (const float*)d_in[33];
    const float* fc1_w      = (const float*)d_in[34];
    const float* fc1_b      = (const float*)d_in[35];
    const float* fc2_w      = (const float*)d_in[36];
    const float* fc2_b      = (const float*)d_in[37];
    (void)in_sizes; (void)n_in; (void)out_size;

    char* base = (char*)d_ws;
    size_t off = 0;
    auto alloc = [&](size_t bytes) -> void* {
        void* p = base + off;
        off += (bytes + 255) & ~(size_t)255;
        return p;
    };
    // persistent (~14 MB)
    float* pe        = (float*)alloc(512 * 256 * 4);
    float* hpe       = (float*)alloc(512 * 256 * 4);
    float* tab_hat   = (float*)alloc(3375 * 8 * 4);
    float* tab2      = (float*)alloc(3375 * 8 * 4);
    float* biasQ2    = (float*)alloc((size_t)8 * 512 * 512 * 4);
    float* ct0       = (float*)alloc(512 * 256 * 4);
    bf16* wb_hqkv  = (bf16*)alloc(768 * 256 * 2);
    bf16* wb_hproj = (bf16*)alloc(256 * 256 * 2);
    bf16* wb_hfc1  = (bf16*)alloc(1024 * 256 * 2);
    bf16* wb_hfc2  = (bf16*)alloc(256 * 1024 * 2);
    bf16* wb_qkv   = (bf16*)alloc(768 * 256 * 2);
    bf16* wb_proj  = (bf16*)alloc(256 * 256 * 2);
    bf16* wb_fc1   = (bf16*)alloc(1024 * 256 * 2);
    bf16* wb_fc2   = (bf16*)alloc(256 * 1024 * 2);
    bf16* wb_pew2  = (bf16*)alloc(256 * 512 * 2);
    bf16* wb_hpew2 = (bf16*)alloc(256 * 512 * 2);
    size_t zstart = off;
    // phase-1 temporaries
    bf16*  hidA      = (bf16*)alloc(512 * 512 * 2);
    bf16*  hidB      = (bf16*)alloc(512 * 512 * 2);
    off = zstart;
    // hat-phase temporaries — dead before xcat is written
    float* biasQ_hat = (float*)alloc((size_t)8 * 512 * 512 * 4);
    bf16*  hct_ln    = (bf16*)alloc(512 * 256 * 2);
    bf16*  hqkv      = (bf16*)alloc(512 * 768 * 2);
    bf16*  hat_attn  = (bf16*)alloc(512 * 256 * 2);
    bf16*  hat_hid   = (bf16*)alloc(512 * 1024 * 2);
    // main-phase buffers overlay hat temporaries; slab count gated on ws_size
    off = zstart;
    float* xcat      = (float*)alloc((size_t)64 * 520 * 256 * 4);   // 34.1 MB
    const int S     = (ws_size >= (size_t)150 * 1024 * 1024) ? 1 : 4;
    const int rows  = 33280 / S;
    const int wins  = 64 / S;
    bf16*  xln_b     = (bf16*)alloc((size_t)rows * 256 * 2);
    char*  region_qa = (char*)alloc((size_t)rows * 1024 * 2);       // qkv+attn, or MLP hidden
    bf16*  qkv_b_    = (bf16*)region_qa;
    bf16*  attn_b    = (bf16*)(region_qa + (size_t)rows * 768 * 2);
    bf16*  hidden    = (bf16*)region_qa;

    // weight conversion (one launch)
    wcvt10_k<<<dim3(1024, 10), 256, 0, stream>>>(hat_qkv_w, hat_proj_w, hat_fc1_w, hat_fc2_w,
                                                 qkv_w, proj_w, fc1_w, fc2_w, pe_w2, hpe_w2,
                                                 wb_hqkv, wb_hproj, wb_hfc1, wb_hfc2,
                                                 wb_qkv, wb_proj, wb_fc1, wb_fc2, wb_pew2, wb_hpew2);

    // pos-emb: hidden build + MFMA gemm (M=512,N=256,K=512, f32 store)
    hidbuild_k<<<dim3(512, 2), 256, 0, stream>>>(pe_w1, pe_b1, hpe_w1, hpe_b1, hidA, hidB);
    gemm_k<3><<<dim3(2, 4), 256, 0, stream>>>(hidA, wb_pew2,  nullptr, 512, 256, 512, pe,  nullptr);
    gemm_k<3><<<dim3(2, 4), 256, 0, stream>>>(hidB, wb_hpew2, nullptr, 512, 256, 512, hpe, nullptr);

    // CPB tables + bias materialize (natural [h][q][k] layout)
    cpbtab_k<<<dim3(3375, 2), 512, 0, stream>>>(hat_cpb_w1, hat_cpb_b1, hat_cpb_w2, tab_hat,
                                                cpb_w1, cpb_b1, cpb_w2, tab2);
    biasbuild_k<<<dim3(8192, 2), 256, 0, stream>>>(tab_hat, biasQ_hat, tab2, biasQ2);

    // hat branch (512 tokens, 1 window, glob=0)
    ct0build_k<<<512, 256, 0, stream>>>(ct, hpe, ct0);
    ln_k<<<512, 256, 0, stream>>>(ct0, hat_n1_g, hat_n1_b, hct_ln);
    gemm_k<0><<<dim3(6, 4), 256, 0, stream>>>(hct_ln, wb_hqkv, hat_qkv_b, 512, 768, 256, nullptr, hqkv);
    flash_k<<<dim3(8, 4), 512, 0, stream>>>(hqkv, biasQ_hat, hat_attn, 512, 0);
    gemm_k<2><<<dim3(2, 4), 256, 0, stream>>>(hat_attn, wb_hproj, hat_proj_b, 512, 256, 256, ct0, nullptr);
    ln_k<<<512, 256, 0, stream>>>(ct0, hat_n2_g, hat_n2_b, hct_ln);
    gemm_k<1><<<dim3(8, 4), 256, 0, stream>>>(hct_ln, wb_hfc1, hat_fc1_b, 512, 1024, 256, nullptr, hat_hid);
    gemm_k<2><<<dim3(2, 4), 256, 0, stream>>>(hat_hid, wb_hfc2, hat_fc2_b, 512, 256, 1024, ct0, nullptr);

    // concat
    xcatbuild_k<<<33280, 256, 0, stream>>>(x, pe, ct0, xcat);

    // main branch: attention (S slabs; S=1 when workspace allows)
    for (int s = 0; s < S; s++) {
        float* xc = xcat + (size_t)s * rows * 256;
        ln_k<<<rows, 256, 0, stream>>>(xc, n1_g, n1_b, xln_b);
        gemm_k<0><<<dim3(6, rows / 128), 256, 0, stream>>>(xln_b, wb_qkv, qkv_b, rows, 768, 256, nullptr, qkv_b_);
        flash_k<<<dim3(wins * 8, 5), 512, 0, stream>>>(qkv_b_, biasQ2, attn_b, 520, 8);
        gemm_k<2><<<dim3(2, rows / 128), 256, 0, stream>>>(attn_b, wb_proj, proj_b, rows, 256, 256, xc, nullptr);
    }
    // MLP (hidden aliases dead qkv/attn region)
    for (int s = 0; s < S; s++) {
        float* xc = xcat + (size_t)s * rows * 256;
        ln_k<<<rows, 256, 0, stream>>>(xc, n2_g, n2_b, xln_b);
        gemm_k<1><<<dim3(8, rows / 128), 256, 0, stream>>>(xln_b, wb_fc1, fc1_b, rows, 1024, 256, nullptr, hidden);
        gemm_k<2><<<dim3(2, rows / 128), 256, 0, stream>>>(hidden, wb_fc2, fc2_b, rows, 256, 1024, xc, nullptr);
    }

    outbuild_k<<<33280, 256, 0, stream>>>(xcat, (float*)d_out);
}